// Round 4
// baseline (218.601 us; speedup 1.0000x reference)
//
#include <hip/hip_runtime.h>
#include <math.h>

#define TT  34   // seq len
#define VV  14   // vocab
#define BLK 256  // threads per block
#define NPB 512  // elements per block (= 256 t-pairs)

typedef float v2f __attribute__((ext_vector_type(2)));
typedef float v4f __attribute__((ext_vector_type(4)));

#if __has_builtin(__builtin_amdgcn_exp2f)
#define EXP2F(x) __builtin_amdgcn_exp2f(x)
#else
#define EXP2F(x) exp2f(x)
#endif
#if __has_builtin(__builtin_amdgcn_rcpf)
#define RCPF(x) __builtin_amdgcn_rcpf(x)
#else
#define RCPF(x) (1.0f/(x))
#endif

static __device__ __forceinline__ v2f fma2(v2f a, v2f b, v2f c) {
    return __builtin_elementwise_fma(a, b, c);   // -> v_pk_fma_f32 on gfx950
}
static __device__ __forceinline__ v2f bc2(float s) { v2f r; r.x = s; r.y = s; return r; }
#define SV2(v, a, b) __builtin_shufflevector((v), (v), (a), (b))
#define LD2(i) (*reinterpret_cast<const v2f*>(&wsm[(i)]))

// wsm layout (floats), all v2f read-bases even (8B-aligned):
//   0..35   owT[j*6+d]   = out_w[d*6+j]
//  36..41   ln2_g        42..47 ln2_b
//  48..59   w1p[d*2+i]   = ffn_w1[i*6+d], i in {0,1}
//  60..65   w1r[d]       = ffn_w1[12+d]
//  66..68   ffn_b1       69 pad
//  70..87   w2T[i*6+d]   = ffn_w2[d*3+i]
//  88..93   ffn_b2       94..95 pad
//  96..107  Gp[d*2+c]    = lnf_g[d]*head_w[c*6+d], c in {0,1}
// 108..113  G2[d]        = lnf_g[d]*head_w[12+d]
// 114..117  pad
// 118..120  eC[c]        = sum_d lnf_b[d]*head_w[c*6+d]
// 121      pad
// 122..163  MT[c*14+v]   = tok_emb[v*3+c]   (fused head rows)
// 164..205  tok_emb natural [v*3+c]
// 206..307  pos_enc natural [t*3+c]

// Per-element epilogue: residual x + attn-out o6 -> 14 logits stored at outp.
// elem1=0: base 16B-aligned -> 3x f4 + f2.  elem1=1: base 8B-aligned -> f2 + 3x f4.
static __device__ __forceinline__ void epi_store(
    const float* __restrict__ wsm, const float o6[6], const float x[6],
    float* __restrict__ outp, int elem1)
{
    v2f X0 = {x[0], x[1]}, X1 = {x[2], x[3]}, X2 = {x[4], x[5]};
    #pragma unroll
    for (int j = 0; j < 6; ++j) {
        const v2f oj = bc2(o6[j]);
        X0 = fma2(oj, LD2(j * 6 + 0), X0);
        X1 = fma2(oj, LD2(j * 6 + 2), X1);
        X2 = fma2(oj, LD2(j * 6 + 4), X2);
    }
    // LN2 + FFN (exact gelu) + residual
    {
        v2f S = X0 + X1 + X2;
        const float mu = (S.x + S.y) * (1.0f / 6.0f);
        const v2f muv = bc2(mu);
        const v2f D0 = X0 - muv, D1 = X1 - muv, D2 = X2 - muv;
        v2f E = fma2(D0, D0, fma2(D1, D1, D2 * D2));
        const float rstd = rsqrtf((E.x + E.y) * (1.0f / 6.0f) + 1e-5f);
        const v2f rs = bc2(rstd);
        const v2f H0 = fma2(D0 * rs, LD2(36), LD2(42));
        const v2f H1 = fma2(D1 * rs, LD2(38), LD2(44));
        const v2f H2 = fma2(D2 * rs, LD2(40), LD2(46));
        const float h[6] = {H0.x, H0.y, H1.x, H1.y, H2.x, H2.y};
        v2f F = LD2(66);
        float f2 = wsm[68];
        #pragma unroll
        for (int d = 0; d < 6; ++d) {
            F  = fma2(bc2(h[d]), LD2(48 + 2 * d), F);
            f2 = fmaf(h[d], wsm[60 + d], f2);
        }
        float g3[3];
        g3[0] = 0.5f * F.x * (1.0f + erff(F.x * 0.70710678118654752f));
        g3[1] = 0.5f * F.y * (1.0f + erff(F.y * 0.70710678118654752f));
        g3[2] = 0.5f * f2  * (1.0f + erff(f2  * 0.70710678118654752f));
        X0 += LD2(88); X1 += LD2(90); X2 += LD2(92);
        #pragma unroll
        for (int i = 0; i < 3; ++i) {
            const v2f gi = bc2(g3[i]);
            X0 = fma2(gi, LD2(70 + i * 6 + 0), X0);
            X1 = fma2(gi, LD2(70 + i * 6 + 2), X1);
            X2 = fma2(gi, LD2(70 + i * 6 + 4), X2);
        }
    }
    // LNF folded into rank-3 head
    v2f lgv[7];
    {
        v2f S = X0 + X1 + X2;
        const float mu = (S.x + S.y) * (1.0f / 6.0f);
        const v2f muv = bc2(mu);
        const v2f D0 = X0 - muv, D1 = X1 - muv, D2 = X2 - muv;
        v2f E = fma2(D0, D0, fma2(D1, D1, D2 * D2));
        const float rstd = rsqrtf((E.x + E.y) * (1.0f / 6.0f) + 1e-5f);
        const float xd[6] = {D0.x, D0.y, D1.x, D1.y, D2.x, D2.y};
        v2f D01 = {0.f, 0.f};
        float d2 = 0.f;
        #pragma unroll
        for (int d = 0; d < 6; ++d) {
            D01 = fma2(bc2(xd[d]), LD2(96 + 2 * d), D01);
            d2  = fmaf(xd[d], wsm[108 + d], d2);
        }
        const v2f y01 = fma2(bc2(rstd), D01, LD2(118));
        const float y2 = fmaf(rstd, d2, wsm[120]);
        const v2f Y0 = bc2(y01.x), Y1 = bc2(y01.y), Y2 = bc2(y2);
        #pragma unroll
        for (int mm = 0; mm < 7; ++mm)
            lgv[mm] = fma2(Y0, LD2(122 + 2 * mm),
                      fma2(Y1, LD2(136 + 2 * mm),
                           Y2 * LD2(150 + 2 * mm)));
    }
    if (!elem1) {
        v4f w0; w0.x = lgv[0].x; w0.y = lgv[0].y; w0.z = lgv[1].x; w0.w = lgv[1].y;
        v4f w1; w1.x = lgv[2].x; w1.y = lgv[2].y; w1.z = lgv[3].x; w1.w = lgv[3].y;
        v4f w2; w2.x = lgv[4].x; w2.y = lgv[4].y; w2.z = lgv[5].x; w2.w = lgv[5].y;
        *reinterpret_cast<v4f*>(outp + 0) = w0;
        *reinterpret_cast<v4f*>(outp + 4) = w1;
        *reinterpret_cast<v4f*>(outp + 8) = w2;
        *reinterpret_cast<v2f*>(outp + 12) = lgv[6];
    } else {
        *reinterpret_cast<v2f*>(outp + 0) = lgv[0];
        v4f w0; w0.x = lgv[1].x; w0.y = lgv[1].y; w0.z = lgv[2].x; w0.w = lgv[2].y;
        v4f w1; w1.x = lgv[3].x; w1.y = lgv[3].y; w1.z = lgv[4].x; w1.w = lgv[4].y;
        v4f w2; w2.x = lgv[5].x; w2.y = lgv[5].y; w2.z = lgv[6].x; w2.w = lgv[6].y;
        *reinterpret_cast<v4f*>(outp + 2)  = w0;
        *reinterpret_cast<v4f*>(outp + 6)  = w1;
        *reinterpret_cast<v4f*>(outp + 10) = w2;
    }
}

// LN1 + q projection from raw x
static __device__ __forceinline__ void make_q(
    const float* __restrict__ ln1_g, const float* __restrict__ ln1_b,
    const float* __restrict__ q_w, const float x[6],
    v2f& Q03, v2f& Q14, v2f& Q25)
{
    float mu = (x[0] + x[1] + x[2] + x[3] + x[4] + x[5]) * (1.0f / 6.0f);
    float var = 0.0f;
    #pragma unroll
    for (int d = 0; d < 6; ++d) { float dd = x[d] - mu; var += dd * dd; }
    const float rstd = rsqrtf(var * (1.0f / 6.0f) + 1e-5f);
    const float h3 = (x[3] - mu) * rstd * ln1_g[3] + ln1_b[3];
    const float h4 = (x[4] - mu) * rstd * ln1_g[4] + ln1_b[4];
    const float h5 = (x[5] - mu) * rstd * ln1_g[5] + ln1_b[5];
    float q[6];
    #pragma unroll
    for (int r = 0; r < 6; ++r)
        q[r] = h3 * q_w[r * 3 + 0] + h4 * q_w[r * 3 + 1] + h5 * q_w[r * 3 + 2];
    Q03.x = q[0]; Q03.y = q[3];
    Q14.x = q[1]; Q14.y = q[4];
    Q25.x = q[2]; Q25.y = q[5];
}

__global__ __launch_bounds__(BLK) void addtx_fwd(
    const int*   __restrict__ idx,
    const float* __restrict__ tok_emb,
    const float* __restrict__ pos_enc,
    const float* __restrict__ q_w,
    const float* __restrict__ k_w,
    const float* __restrict__ v_w,
    const float* __restrict__ out_w,
    const float* __restrict__ ln1_g, const float* __restrict__ ln1_b,
    const float* __restrict__ ln2_g, const float* __restrict__ ln2_b,
    const float* __restrict__ lnf_g, const float* __restrict__ lnf_b,
    const float* __restrict__ ffn_w1, const float* __restrict__ ffn_b1,
    const float* __restrict__ ffn_w2, const float* __restrict__ ffn_b2,
    const float* __restrict__ head_w,
    float* __restrict__ out, int n)
{
    // kv entry e=(pos,tok), pair-interleaved, k pre-scaled 1/sqrt(3)*log2e:
    //  f4[0]=(k0,k3,k1,k4)  f4[1]=(k2,k5,v0,v3)  f4[2]=(v1,v4,v2,v5)
    __shared__ v4f   kvs[TT * VV * 3];   // 22848 B
    __shared__ float wsm[308];           //  1232 B
    __shared__ int   idsb[17 * TT];      //  2312 B  (<=16 rows used + prefetch slack)

    const int tid = threadIdx.x;
    const int blk = blockIdx.x;

    // ---------------- stage weights (transposed / pair-interleaved) ----------------
    for (int i = tid; i < 308; i += BLK) {
        float val = 0.0f;
        if (i < 36)       { const int j = i / 6, d = i - j * 6; val = out_w[d * 6 + j]; }
        else if (i < 42)  val = ln2_g[i - 36];
        else if (i < 48)  val = ln2_b[i - 42];
        else if (i < 60)  { const int k = i - 48, d = k >> 1, ii = k & 1; val = ffn_w1[ii * 6 + d]; }
        else if (i < 66)  val = ffn_w1[12 + (i - 60)];
        else if (i < 69)  val = ffn_b1[i - 66];
        else if (i < 70)  val = 0.0f;
        else if (i < 88)  { const int k = i - 70, ii = k / 6, d = k - ii * 6; val = ffn_w2[d * 3 + ii]; }
        else if (i < 94)  val = ffn_b2[i - 88];
        else if (i < 96)  val = 0.0f;
        else if (i < 108) { const int k = i - 96, d = k >> 1, c = k & 1; val = lnf_g[d] * head_w[c * 6 + d]; }
        else if (i < 114) { const int d = i - 108; val = lnf_g[d] * head_w[12 + d]; }
        else if (i < 118) val = 0.0f;
        else if (i < 121) { const int c = i - 118; float s = 0.0f;
                            #pragma unroll
                            for (int d = 0; d < 6; ++d) s += lnf_b[d] * head_w[c * 6 + d];
                            val = s; }
        else if (i < 122) val = 0.0f;
        else if (i < 164) { const int k = i - 122, c = k / 14, v = k - c * 14; val = tok_emb[v * 3 + c]; }
        else if (i < 206) val = tok_emb[i - 164];
        else              val = pos_enc[i - 206];
        wsm[i] = val;
    }

    // ---------------- stage this block's token ids (coalesced), pre-scaled *48 ----------------
    const int p0 = blk * BLK;            // first global pair index
    const int b0 = p0 / 17;              // first sequence
    {
        const int gb = b0 * TT;
        for (int e = tid; e < 17 * TT; e += BLK) {
            const int g = gb + e;
            idsb[e] = (g < n) ? (idx[g] * 48) : 0;
        }
    }

    // ---------------- build (pos,tok) -> k,v table ----------------
    const float rs3l = 0.57735026918962576f * 1.4426950408889634f; // 1/sqrt(3)*log2e
    for (int e = tid; e < TT * VV; e += BLK) {
        const int pos = e / VV, id = e - pos * VV;
        float x[6];
        x[0] = tok_emb[id * 3 + 0]; x[1] = tok_emb[id * 3 + 1]; x[2] = tok_emb[id * 3 + 2];
        x[3] = pos_enc[pos * 3 + 0]; x[4] = pos_enc[pos * 3 + 1]; x[5] = pos_enc[pos * 3 + 2];
        float mu = (x[0] + x[1] + x[2] + x[3] + x[4] + x[5]) * (1.0f / 6.0f);
        float var = 0.0f;
        #pragma unroll
        for (int d = 0; d < 6; ++d) { float dd = x[d] - mu; var += dd * dd; }
        const float rstd = rsqrtf(var * (1.0f / 6.0f) + 1e-5f);
        float h[6];
        #pragma unroll
        for (int d = 0; d < 6; ++d) h[d] = (x[d] - mu) * rstd * ln1_g[d] + ln1_b[d];
        float kk[6], vvv[6];
        #pragma unroll
        for (int r = 0; r < 6; ++r) {
            kk[r]  = (h[3] * k_w[r * 3 + 0] + h[4] * k_w[r * 3 + 1] + h[5] * k_w[r * 3 + 2]) * rs3l;
            vvv[r] =  h[0] * v_w[r * 3 + 0] + h[1] * v_w[r * 3 + 1] + h[2] * v_w[r * 3 + 2];
        }
        v4f f0; f0.x = kk[0]; f0.y = kk[3]; f0.z = kk[1]; f0.w = kk[4];
        v4f f1; f1.x = kk[2]; f1.y = kk[5]; f1.z = vvv[0]; f1.w = vvv[3];
        v4f f2; f2.x = vvv[1]; f2.y = vvv[4]; f2.z = vvv[2]; f2.w = vvv[5];
        kvs[e * 3 + 0] = f0;
        kvs[e * 3 + 1] = f1;
        kvs[e * 3 + 2] = f2;
    }
    __syncthreads();

    // ---------------- u-balanced pair remap (closed form, mod 17) ----------------
    // Pair p = blk*256 + pl: b = p/17, u = p%17 (since 2*17=34). Sorted-by-u
    // contiguous rank assignment; count(u) = 16 iff u==r0 else 15.
    const int srank = (tid + ((blk & 3) << 6)) & (BLK - 1);
    const int r0 = p0 % 17;
    const int thrA = 15 * r0;
    int u, k;
    if (srank < thrA)           { u = srank / 15;      k = srank - 15 * u; }
    else if (srank < thrA + 16) { u = r0;              k = srank - thrA;   }
    else                        { const int rr = srank - 1; u = rr / 15; k = rr - 15 * u; }
    int dd17 = u - r0; if (dd17 < 0) dd17 += 17;
    const int pl = dd17 + 17 * k;        // bijection of srank over [0,256)
    const int p  = p0 + pl;
    const int b  = p / 17;
    const int t0 = 2 * (p - b * 17);     // even t
    const int t1 = t0 + 1;
    const int* __restrict__ rowL = idsb + (b - b0) * TT;   // values = id*48

    // ---------------- own x (pre-LN residual) and q for both elements ----------------
    float xa[6], xb[6];
    {
        const int ta3 = rowL[t0] >> 4;   // id*3
        const int tb3 = rowL[t1] >> 4;
        xa[0] = wsm[164 + ta3]; xa[1] = wsm[165 + ta3]; xa[2] = wsm[166 + ta3];
        xb[0] = wsm[164 + tb3]; xb[1] = wsm[165 + tb3]; xb[2] = wsm[166 + tb3];
        xa[3] = wsm[206 + t0 * 3]; xa[4] = wsm[207 + t0 * 3]; xa[5] = wsm[208 + t0 * 3];
        xb[3] = wsm[206 + t1 * 3]; xb[4] = wsm[207 + t1 * 3]; xb[5] = wsm[208 + t1 * 3];
    }
    v2f Q03a, Q14a, Q25a, Q03b, Q14b, Q25b;
    make_q(ln1_g, ln1_b, q_w, xa, Q03a, Q14a, Q25a);
    make_q(ln1_g, ln1_b, q_w, xb, Q03b, Q14b, Q25b);

    // ---------------- causal attention for the pair: one kv read, two elements ----------------
    v2f La = {0.f, 0.f}, A0a = {0.f, 0.f}, A1a = {0.f, 0.f}, A2a = {0.f, 0.f};
    v2f Lb = {0.f, 0.f}, A0b = {0.f, 0.f}, A1b = {0.f, 0.f}, A2b = {0.f, 0.f};
    int ids48 = rowL[0];
    const char* kp = (const char*)kvs;
    for (int s = 0; s <= t0; ++s) {
        const v4f* e4 = (const v4f*)(kp + ids48);
        const v4f ka = e4[0], kb = e4[1], vb = e4[2];
        ids48 = rowL[s + 1];                 // in-row (s+1 <= t1 <= 33)
        const v2f ka01 = SV2(ka, 0, 1), ka23 = SV2(ka, 2, 3);
        const v2f kb01 = SV2(kb, 0, 1), kb23 = SV2(kb, 2, 3);
        const v2f vb01 = SV2(vb, 0, 1), vb23 = SV2(vb, 2, 3);
        v2f sa = fma2(Q03a, ka01, fma2(Q14a, ka23, Q25a * kb01));
        v2f sb = fma2(Q03b, ka01, fma2(Q14b, ka23, Q25b * kb01));
        v2f pa; pa.x = EXP2F(sa.x); pa.y = EXP2F(sa.y);
        v2f pb; pb.x = EXP2F(sb.x); pb.y = EXP2F(sb.y);
        La += pa; Lb += pb;
        A0a = fma2(pa, kb23, A0a); A0b = fma2(pb, kb23, A0b);
        A1a = fma2(pa, vb01, A1a); A1b = fma2(pb, vb01, A1b);
        A2a = fma2(pa, vb23, A2a); A2b = fma2(pb, vb23, A2b);
        kp += VV * 48;
    }
    // solo iteration s = t1 for element b (ids48 already = rowL[t1])
    {
        const v4f* e4 = (const v4f*)(kp + ids48);
        const v4f ka = e4[0], kb = e4[1], vb = e4[2];
        v2f sb = fma2(Q03b, SV2(ka, 0, 1),
                 fma2(Q14b, SV2(ka, 2, 3), Q25b * SV2(kb, 0, 1)));
        v2f pb; pb.x = EXP2F(sb.x); pb.y = EXP2F(sb.y);
        Lb += pb;
        A0b = fma2(pb, SV2(kb, 2, 3), A0b);
        A1b = fma2(pb, SV2(vb, 0, 1), A1b);
        A2b = fma2(pb, SV2(vb, 2, 3), A2b);
    }

    v2f Ia; Ia.x = RCPF(La.x); Ia.y = RCPF(La.y);
    v2f Ib; Ib.x = RCPF(Lb.x); Ib.y = RCPF(Lb.y);
    const v2f Oa0 = A0a * Ia, Oa1 = A1a * Ia, Oa2 = A2a * Ia;
    const v2f Ob0 = A0b * Ib, Ob1 = A1b * Ib, Ob2 = A2b * Ib;
    const float o6a[6] = {Oa0.x, Oa1.x, Oa2.x, Oa0.y, Oa1.y, Oa2.y};
    const float o6b[6] = {Ob0.x, Ob1.x, Ob2.x, Ob0.y, Ob1.y, Ob2.y};

    // ---------------- epilogues + direct coalesced-ish stores (28 contiguous floats) ----------------
    float* __restrict__ outp = out + (size_t)(b * TT + t0) * VV;
    epi_store(wsm, o6a, xa, outp,      0);
    epi_store(wsm, o6b, xb, outp + VV, 1);
}

extern "C" void kernel_launch(void* const* d_in, const int* in_sizes, int n_in,
                              void* d_out, int out_size, void* d_ws, size_t ws_size,
                              hipStream_t stream) {
    const int*   idx     = (const int*)  d_in[0];
    const float* tok_emb = (const float*)d_in[1];
    const float* pos_enc = (const float*)d_in[2];
    const float* q_w     = (const float*)d_in[3];
    const float* k_w     = (const float*)d_in[4];
    const float* v_w     = (const float*)d_in[5];
    const float* out_w   = (const float*)d_in[6];
    const float* ln1_g   = (const float*)d_in[7];
    const float* ln1_b   = (const float*)d_in[8];
    const float* ln2_g   = (const float*)d_in[9];
    const float* ln2_b   = (const float*)d_in[10];
    const float* lnf_g   = (const float*)d_in[11];
    const float* lnf_b   = (const float*)d_in[12];
    const float* ffn_w1  = (const float*)d_in[13];
    const float* ffn_b1  = (const float*)d_in[14];
    const float* ffn_w2  = (const float*)d_in[15];
    const float* ffn_b2  = (const float*)d_in[16];
    const float* head_w  = (const float*)d_in[17];
    float* out = (float*)d_out;

    const int n = in_sizes[0];        // B*T = 65536*34 = 2228224, divisible by 512
    const int blocks = n / NPB;       // 4352
    addtx_fwd<<<blocks, BLK, 0, stream>>>(idx, tok_emb, pos_enc, q_w, k_w, v_w, out_w,
                                          ln1_g, ln1_b, ln2_g, ln2_b, lnf_g, lnf_b,
                                          ffn_w1, ffn_b1, ffn_w2, ffn_b2, head_w, out, n);
}

// Round 5
// 212.151 us; speedup vs baseline: 1.0304x; 1.0304x over previous
//
#include <hip/hip_runtime.h>
#include <math.h>

#define TT  34   // seq len
#define VV  14   // vocab
#define BLK 512  // threads per block (8 waves), one element per thread

typedef float v2f __attribute__((ext_vector_type(2)));
typedef float v4f __attribute__((ext_vector_type(4)));

#if __has_builtin(__builtin_amdgcn_exp2f)
#define EXP2F(x) __builtin_amdgcn_exp2f(x)
#else
#define EXP2F(x) exp2f(x)
#endif
#if __has_builtin(__builtin_amdgcn_rcpf)
#define RCPF(x) __builtin_amdgcn_rcpf(x)
#else
#define RCPF(x) (1.0f/(x))
#endif

static __device__ __forceinline__ v2f fma2(v2f a, v2f b, v2f c) {
    return __builtin_elementwise_fma(a, b, c);   // -> v_pk_fma_f32 on gfx950
}
static __device__ __forceinline__ v2f bc2(float s) { v2f r; r.x = s; r.y = s; return r; }
#define SV2(v, a, b) __builtin_shufflevector((v), (v), (a), (b))

// wsm layout (floats), all v2f read-bases even (8B-aligned):
//   0..35   owT[j*6+d]   = out_w[d*6+j]
//  36..41   ln2_g        42..47 ln2_b
//  48..59   w1p[d*2+i]   = ffn_w1[i*6+d], i in {0,1}
//  60..65   w1r[d]       = ffn_w1[12+d]
//  66..68   ffn_b1       69 pad
//  70..87   w2T[i*6+d]   = ffn_w2[d*3+i]
//  88..93   ffn_b2       94..95 pad
//  96..107  Gp[d*2+c]    = lnf_g[d]*head_w[c*6+d], c in {0,1}
// 108..113  G2[d]        = lnf_g[d]*head_w[12+d]
// 114..117  pad
// 118..120  eC[c]        = sum_d lnf_b[d]*head_w[c*6+d]
// 121      pad
// 122..163  MT[c*14+v]   = tok_emb[v*3+c]   (fused head rows)
// 164..205  tok_emb natural [v*3+c]
// 206..307  pos_enc natural [t*3+c]

__global__ __launch_bounds__(BLK, 8) void addtx_fwd(
    const int*   __restrict__ idx,
    const float* __restrict__ tok_emb,
    const float* __restrict__ pos_enc,
    const float* __restrict__ q_w,
    const float* __restrict__ k_w,
    const float* __restrict__ v_w,
    const float* __restrict__ out_w,
    const float* __restrict__ ln1_g, const float* __restrict__ ln1_b,
    const float* __restrict__ ln2_g, const float* __restrict__ ln2_b,
    const float* __restrict__ lnf_g, const float* __restrict__ lnf_b,
    const float* __restrict__ ffn_w1, const float* __restrict__ ffn_b1,
    const float* __restrict__ ffn_w2, const float* __restrict__ ffn_b2,
    const float* __restrict__ head_w,
    float* __restrict__ out, int n)
{
    // kv entry e=(pos,tok), pair-interleaved for packed math, k pre-scaled 1/sqrt(3)*log2e:
    //  f4[0]=(k0,k3,k1,k4)  f4[1]=(k2,k5,v0,v3)  f4[2]=(v1,v4,v2,v5)
    // First TT*VV*3=1428 entries are the kv table; the array is oversized to 1792
    // (28672B) because it is reused as the 512x14-float logits staging buffer.
    __shared__ v4f   kvs[1792];          // 28672 B (kv table 22848 B | logits 28672 B)
    __shared__ float wsm[308];           //  1232 B
    __shared__ int   idsb[594];          //  2376 B  (<=17 rows x 34 + prefetch slack)

    const int tid = threadIdx.x;
    const int blk = blockIdx.x;

    // ---------------- stage weights (transposed / pair-interleaved) ----------------
    if (tid < 308) {
        const int i = tid;
        float val = 0.0f;
        if (i < 36)       { const int j = i / 6, d = i - j * 6; val = out_w[d * 6 + j]; }
        else if (i < 42)  val = ln2_g[i - 36];
        else if (i < 48)  val = ln2_b[i - 42];
        else if (i < 60)  { const int k = i - 48, d = k >> 1, ii = k & 1; val = ffn_w1[ii * 6 + d]; }
        else if (i < 66)  val = ffn_w1[12 + (i - 60)];
        else if (i < 69)  val = ffn_b1[i - 66];
        else if (i < 70)  val = 0.0f;
        else if (i < 88)  { const int k = i - 70, ii = k / 6, d = k - ii * 6; val = ffn_w2[d * 3 + ii]; }
        else if (i < 94)  val = ffn_b2[i - 88];
        else if (i < 96)  val = 0.0f;
        else if (i < 108) { const int k = i - 96, d = k >> 1, c = k & 1; val = lnf_g[d] * head_w[c * 6 + d]; }
        else if (i < 114) { const int d = i - 108; val = lnf_g[d] * head_w[12 + d]; }
        else if (i < 118) val = 0.0f;
        else if (i < 121) { const int c = i - 118; float s = 0.0f;
                            #pragma unroll
                            for (int d = 0; d < 6; ++d) s += lnf_b[d] * head_w[c * 6 + d];
                            val = s; }
        else if (i < 122) val = 0.0f;
        else if (i < 164) { const int k = i - 122, c = k / 14, v = k - c * 14; val = tok_emb[v * 3 + c]; }
        else if (i < 206) val = tok_emb[i - 164];
        else              val = pos_enc[i - 206];
        wsm[i] = val;
    }

    // ---------------- stage this block's token ids (coalesced), pre-scaled *48 ----------------
    const int p0 = blk * BLK;            // first global element index
    const int b0 = p0 / TT;              // first sequence
    {
        const int gb = b0 * TT;
        for (int e = tid; e < 594; e += BLK) {
            const int g = gb + e;
            idsb[e] = (g < n) ? (idx[g] * 48) : 0;
        }
    }

    // ---------------- build (pos,tok) -> k,v table ----------------
    const float rs3l = 0.57735026918962576f * 1.4426950408889634f; // 1/sqrt(3)*log2e
    for (int e = tid; e < TT * VV; e += BLK) {
        const int pos = e / VV, id = e - pos * VV;
        float x[6];
        x[0] = tok_emb[id * 3 + 0]; x[1] = tok_emb[id * 3 + 1]; x[2] = tok_emb[id * 3 + 2];
        x[3] = pos_enc[pos * 3 + 0]; x[4] = pos_enc[pos * 3 + 1]; x[5] = pos_enc[pos * 3 + 2];
        float mu = (x[0] + x[1] + x[2] + x[3] + x[4] + x[5]) * (1.0f / 6.0f);
        float var = 0.0f;
        #pragma unroll
        for (int d = 0; d < 6; ++d) { float dd = x[d] - mu; var += dd * dd; }
        const float rstd = rsqrtf(var * (1.0f / 6.0f) + 1e-5f);
        float h[6];
        #pragma unroll
        for (int d = 0; d < 6; ++d) h[d] = (x[d] - mu) * rstd * ln1_g[d] + ln1_b[d];
        float kk[6], vvv[6];
        #pragma unroll
        for (int r = 0; r < 6; ++r) {
            kk[r]  = (h[3] * k_w[r * 3 + 0] + h[4] * k_w[r * 3 + 1] + h[5] * k_w[r * 3 + 2]) * rs3l;
            vvv[r] =  h[0] * v_w[r * 3 + 0] + h[1] * v_w[r * 3 + 1] + h[2] * v_w[r * 3 + 2];
        }
        v4f f0; f0.x = kk[0]; f0.y = kk[3]; f0.z = kk[1]; f0.w = kk[4];
        v4f f1; f1.x = kk[2]; f1.y = kk[5]; f1.z = vvv[0]; f1.w = vvv[3];
        v4f f2; f2.x = vvv[1]; f2.y = vvv[4]; f2.z = vvv[2]; f2.w = vvv[5];
        kvs[e * 3 + 0] = f0;
        kvs[e * 3 + 1] = f1;
        kvs[e * 3 + 2] = f2;
    }
    __syncthreads();

    // ---------------- t-balanced intra-block remap (closed form, BLK=512) ----------------
    // 512 = 34*15 + 2, so groups dlt=(t-r0) mod 34 have count 16 for dlt in {0,1},
    // 15 otherwise. r0 = (blk*512) % 34 = 2*blk mod 34 is always EVEN <= 32, so the
    // two 16-count t's are exactly {r0, r0+1} (no wrap). Ranks assigned in t order:
    //   t in [0,r0):   ranks [0, 15*r0)            count 15
    //   t in {r0,r0+1}: ranks [15*r0, 15*r0+32)    count 16
    //   t in [r0+2,34): ranks [15*r0+32, 512)      count 15
    const int srank = (tid + ((blk & 7) << 6)) & (BLK - 1);
    const int r0 = p0 % TT;
    const int thrA = 15 * r0;
    int t, dlt, ksel;
    if (srank < thrA)           { t = srank / 15; ksel = srank - 15 * t; dlt = t - r0 + TT; }
    else if (srank < thrA + 32) { const int rr = srank - thrA; dlt = rr >> 4; ksel = rr & 15; t = r0 + dlt; }
    else                        { const int rr = srank - thrA - 32; const int qq = rr / 15;
                                  ksel = rr - 15 * qq; dlt = 2 + qq; t = r0 + dlt; }
    const int il   = dlt + TT * ksel;    // local slot in [0,512), bijection of tid
    const int flat = p0 + il;
    const int b    = flat / TT;          // note: flat % TT == t by construction
    const int* __restrict__ rowL = idsb + (b - b0) * TT;   // LDS-resident, values = id*48

    // ---------------- own x (pre-LN residual) and q ----------------
    float x[6];
    {
        const int tb = rowL[t] >> 4;   // id*3
        x[0] = wsm[164 + tb]; x[1] = wsm[165 + tb]; x[2] = wsm[166 + tb];
        x[3] = wsm[206 + t * 3]; x[4] = wsm[207 + t * 3]; x[5] = wsm[208 + t * 3];
    }
    float q[6];
    {
        float mu = (x[0] + x[1] + x[2] + x[3] + x[4] + x[5]) * (1.0f / 6.0f);
        float var = 0.0f;
        #pragma unroll
        for (int d = 0; d < 6; ++d) { float dd = x[d] - mu; var += dd * dd; }
        const float rstd = rsqrtf(var * (1.0f / 6.0f) + 1e-5f);
        const float h3 = (x[3] - mu) * rstd * ln1_g[3] + ln1_b[3];
        const float h4 = (x[4] - mu) * rstd * ln1_g[4] + ln1_b[4];
        const float h5 = (x[5] - mu) * rstd * ln1_g[5] + ln1_b[5];
        #pragma unroll
        for (int r = 0; r < 6; ++r)
            q[r] = h3 * q_w[r * 3 + 0] + h4 * q_w[r * 3 + 1] + h5 * q_w[r * 3 + 2];
    }
    const v2f Q03 = {q[0], q[3]}, Q14 = {q[1], q[4]}, Q25 = {q[2], q[5]};

    // ---------------- causal attention, packed 2-head exp-sum softmax ----------------
    // Scores bounded -> plain exp-sum == softmax in fp32. k carries the log2e scale.
    // ids prefetched one iteration ahead; all score/accum math is v_pk_fma_f32.
    v2f L = {0.f, 0.f}, A0 = {0.f, 0.f}, A1 = {0.f, 0.f}, A2 = {0.f, 0.f};
    int ids48 = rowL[0];
    const char* kp = (const char*)kvs;
    for (int s = 0; s <= t; ++s) {
        const v4f* e4 = (const v4f*)(kp + ids48);
        const v4f ka = e4[0], kb = e4[1], vb = e4[2];
        ids48 = rowL[s + 1];                     // safe: idsb padded to 594
        v2f sc = fma2(Q03, SV2(ka, 0, 1),
                 fma2(Q14, SV2(ka, 2, 3),
                      Q25 * SV2(kb, 0, 1)));
        v2f p; p.x = EXP2F(sc.x); p.y = EXP2F(sc.y);
        L += p;
        A0 = fma2(p, SV2(kb, 2, 3), A0);
        A1 = fma2(p, SV2(vb, 0, 1), A1);
        A2 = fma2(p, SV2(vb, 2, 3), A2);
        kp += VV * 48;
    }
    v2f I; I.x = RCPF(L.x); I.y = RCPF(L.y);
    const v2f O0 = A0 * I, O1 = A1 * I, O2 = A2 * I;
    const float o6[6] = {O0.x, O1.x, O2.x, O0.y, O1.y, O2.y};

    // ---------------- residual + out proj (packed over d-pairs) ----------------
    v2f X0 = {x[0], x[1]}, X1 = {x[2], x[3]}, X2 = {x[4], x[5]};
    #define LD2(i) (*reinterpret_cast<const v2f*>(&wsm[(i)]))
    #pragma unroll
    for (int j = 0; j < 6; ++j) {
        const v2f oj = bc2(o6[j]);
        X0 = fma2(oj, LD2(j * 6 + 0), X0);
        X1 = fma2(oj, LD2(j * 6 + 2), X1);
        X2 = fma2(oj, LD2(j * 6 + 4), X2);
    }

    // ---------------- LN2 + FFN (exact gelu) + residual, packed ----------------
    {
        v2f S = X0 + X1 + X2;
        const float mu = (S.x + S.y) * (1.0f / 6.0f);
        const v2f muv = bc2(mu);
        const v2f D0 = X0 - muv, D1 = X1 - muv, D2 = X2 - muv;
        v2f E = fma2(D0, D0, fma2(D1, D1, D2 * D2));
        const float rstd = rsqrtf((E.x + E.y) * (1.0f / 6.0f) + 1e-5f);
        const v2f rs = bc2(rstd);
        const v2f H0 = fma2(D0 * rs, LD2(36), LD2(42));
        const v2f H1 = fma2(D1 * rs, LD2(38), LD2(44));
        const v2f H2 = fma2(D2 * rs, LD2(40), LD2(46));
        const float h[6] = {H0.x, H0.y, H1.x, H1.y, H2.x, H2.y};
        v2f F = LD2(66);
        float f2 = wsm[68];
        #pragma unroll
        for (int d = 0; d < 6; ++d) {
            F  = fma2(bc2(h[d]), LD2(48 + 2 * d), F);
            f2 = fmaf(h[d], wsm[60 + d], f2);
        }
        float g3[3];
        g3[0] = 0.5f * F.x * (1.0f + erff(F.x * 0.70710678118654752f));
        g3[1] = 0.5f * F.y * (1.0f + erff(F.y * 0.70710678118654752f));
        g3[2] = 0.5f * f2  * (1.0f + erff(f2  * 0.70710678118654752f));
        X0 += LD2(88); X1 += LD2(90); X2 += LD2(92);
        #pragma unroll
        for (int i = 0; i < 3; ++i) {
            const v2f gi = bc2(g3[i]);
            X0 = fma2(gi, LD2(70 + i * 6 + 0), X0);
            X1 = fma2(gi, LD2(70 + i * 6 + 2), X1);
            X2 = fma2(gi, LD2(70 + i * 6 + 4), X2);
        }
    }

    // ---------------- LNF folded into rank-3 head, packed ----------------
    v2f lgv[7];
    {
        v2f S = X0 + X1 + X2;
        const float mu = (S.x + S.y) * (1.0f / 6.0f);
        const v2f muv = bc2(mu);
        const v2f D0 = X0 - muv, D1 = X1 - muv, D2 = X2 - muv;
        v2f E = fma2(D0, D0, fma2(D1, D1, D2 * D2));
        const float rstd = rsqrtf((E.x + E.y) * (1.0f / 6.0f) + 1e-5f);
        const float xd[6] = {D0.x, D0.y, D1.x, D1.y, D2.x, D2.y};
        v2f D01 = {0.f, 0.f};
        float d2 = 0.f;
        #pragma unroll
        for (int d = 0; d < 6; ++d) {
            D01 = fma2(bc2(xd[d]), LD2(96 + 2 * d), D01);
            d2  = fmaf(xd[d], wsm[108 + d], d2);
        }
        const v2f y01 = fma2(bc2(rstd), D01, LD2(118));
        const float y2 = fmaf(rstd, d2, wsm[120]);
        const v2f Y0 = bc2(y01.x), Y1 = bc2(y01.y), Y2 = bc2(y2);
        #pragma unroll
        for (int mm = 0; mm < 7; ++mm)
            lgv[mm] = fma2(Y0, LD2(122 + 2 * mm),
                      fma2(Y1, LD2(136 + 2 * mm),
                           Y2 * LD2(150 + 2 * mm)));
    }
    __syncthreads();   // kvs readers done

    // ---------------- stage logits over kvs (dead) + coalesced writeout ----------------
    v2f* lg2 = reinterpret_cast<v2f*>(kvs);
    #pragma unroll
    for (int j = 0; j < 7; ++j)
        lg2[il * 7 + j] = lgv[j];
    __syncthreads();
    const v2f* s2 = reinterpret_cast<const v2f*>(kvs);
    v2f* __restrict__ ob2 = reinterpret_cast<v2f*>(out + (size_t)blk * (BLK * VV));
    #pragma unroll
    for (int j = 0; j < 7; ++j)
        ob2[j * BLK + tid] = s2[j * BLK + tid];
}

extern "C" void kernel_launch(void* const* d_in, const int* in_sizes, int n_in,
                              void* d_out, int out_size, void* d_ws, size_t ws_size,
                              hipStream_t stream) {
    const int*   idx     = (const int*)  d_in[0];
    const float* tok_emb = (const float*)d_in[1];
    const float* pos_enc = (const float*)d_in[2];
    const float* q_w     = (const float*)d_in[3];
    const float* k_w     = (const float*)d_in[4];
    const float* v_w     = (const float*)d_in[5];
    const float* out_w   = (const float*)d_in[6];
    const float* ln1_g   = (const float*)d_in[7];
    const float* ln1_b   = (const float*)d_in[8];
    const float* ln2_g   = (const float*)d_in[9];
    const float* ln2_b   = (const float*)d_in[10];
    const float* lnf_g   = (const float*)d_in[11];
    const float* lnf_b   = (const float*)d_in[12];
    const float* ffn_w1  = (const float*)d_in[13];
    const float* ffn_b1  = (const float*)d_in[14];
    const float* ffn_w2  = (const float*)d_in[15];
    const float* ffn_b2  = (const float*)d_in[16];
    const float* head_w  = (const float*)d_in[17];
    float* out = (float*)d_out;

    const int n = in_sizes[0];        // B*T = 65536*34 = 2228224, divisible by 512
    const int blocks = n / BLK;       // 4352
    addtx_fwd<<<blocks, BLK, 0, stream>>>(idx, tok_emb, pos_enc, q_w, k_w, v_w, out_w,
                                          ln1_g, ln1_b, ln2_g, ln2_b, lnf_g, lnf_b,
                                          ffn_w1, ffn_b1, ffn_w2, ffn_b2, head_w, out, n);
}